// Round 8
// baseline (13489.154 us; speedup 1.0000x reference)
//
#include <hip/hip_runtime.h>
#include <stdint.h>

typedef __attribute__((ext_vector_type(8))) short short8;
typedef __attribute__((ext_vector_type(4))) float f32x4;
typedef __attribute__((ext_vector_type(4))) unsigned u32x4;

#define T_SZ 512

// ws layout (bytes)
#define XP_OFF    0ull                 // xp (bf16): 16384*4096*2 = 134217728
#define UPERM_OFF 134217728ull         // Uperm (bf16): 8 MB
#define WPERM_OFF 142606336ull         // Wperm (bf16): 4 MB
#define HBUF_OFF  146800640ull         // fast hbuf: 8 teams x 4 slabs x 4 batch x 1024 dwords = 512 KB
#define SHAD_OFF  147324928ull         // shadow hbuf (LLC), same layout = 512 KB
#define CTL_OFF   147849216ull         // 16 control dwords (XCD claim table)

static __device__ __forceinline__ float b2f(unsigned short u) {
  unsigned v = ((unsigned)u) << 16;
  return __builtin_bit_cast(float, v);
}
static __device__ __forceinline__ unsigned short f2b(float f) {
  unsigned u = __builtin_bit_cast(unsigned, f);
  u += 0x7fffu + ((u >> 16) & 1u);   // RNE
  return (unsigned short)(u >> 16);
}
static __device__ __forceinline__ float sigm(float x) {
  return 1.0f / (1.0f + __expf(-x));
}
static __device__ __forceinline__ float tanh_f(float x) {
  return 1.0f - 2.0f / (__expf(2.0f * x) + 1.0f);
}

// ---- one-time permutation of U (f32 -> bf16) into MFMA B-fragment layout ----
__global__ void permute_U(const float* __restrict__ U, unsigned short* __restrict__ Up) {
  int t = blockIdx.x * 256 + threadIdx.x;        // 524288 threads
  int l = t & 63;
  int F = t >> 6;                                 // 8192 frags
  int kk = F & 7, g = (F >> 3) & 3, kq = (F >> 5) & 3, cg = F >> 7;
  int k0 = kq * 256 + kk * 32 + (l >> 4) * 8;
  int n  = g * 1024 + cg * 16 + (l & 15);
  unsigned short v[8];
#pragma unroll
  for (int j = 0; j < 8; j++) v[j] = f2b(U[(size_t)(k0 + j) * 4096 + n]);
  unsigned short* dst = Up + (size_t)t * 8;
#pragma unroll
  for (int j = 0; j < 8; j++) dst[j] = v[j];
}

__global__ void permute_W(const float* __restrict__ W, unsigned short* __restrict__ Wp) {
  int t = blockIdx.x * 256 + threadIdx.x;        // 262144 threads
  int l = t & 63;
  int F = t >> 6;                                 // 4096 frags
  int kk = F & 15, nt = F >> 4;
  int k0 = kk * 32 + (l >> 4) * 8;
  int n  = nt * 16 + (l & 15);
  unsigned short v[8];
#pragma unroll
  for (int j = 0; j < 8; j++) v[j] = f2b(W[(size_t)(k0 + j) * 4096 + n]);
  unsigned short* dst = Wp + (size_t)t * 8;
#pragma unroll
  for (int j = 0; j < 8; j++) dst[j] = v[j];
}

// hbuf/shadow: per team, slab 0 = (h=0, tag=0); slabs 1..3 = tag 0xFFFF.
// ctl: claim counters + check-in, zeroed.
__global__ void init_hbuf(unsigned* __restrict__ hbuf, unsigned* __restrict__ shad,
                          unsigned* __restrict__ ctl) {
  int t = blockIdx.x * 256 + threadIdx.x;        // 1025*256 threads
  if (t < 131072) hbuf[t] = (((t >> 12) & 3) == 0) ? 0u : 0xFFFFu;
  else if (t < 262144) { int u = t - 131072; shad[u] = (((u >> 12) & 3) == 0) ? 0u : 0xFFFFu; }
  else if (t < 262160) ctl[t - 262144] = 0u;
}

// ---- Phase B: xp[m][n] = X[m][:] @ W[:][n] + b[n], M=16384 N=4096 K=512 ----
__global__ __launch_bounds__(256) void xproj_gemm(
    const float* __restrict__ X,
    const unsigned short* __restrict__ Wp,
    const float* __restrict__ bias,
    unsigned short* __restrict__ xp) {
  const int tid = threadIdx.x;
  const int l = tid & 63;
  const int w = tid >> 6;
  const int wr = w >> 1, wc = w & 1;
  const int bn = blockIdx.x;   // 32
  const int bm = blockIdx.y;   // 128
  const int quad = l >> 4, lane16 = l & 15;
  __shared__ unsigned short lA[128 * 72];

  f32x4 acc[4][4];
#pragma unroll
  for (int i = 0; i < 4; i++)
#pragma unroll
    for (int j = 0; j < 4; j++) acc[i][j] = (f32x4){0.f, 0.f, 0.f, 0.f};

  const int m0 = bm * 128;
  const int sr = tid >> 3;
  const int sc = (tid & 7) * 8;

  for (int ks = 0; ks < 8; ks++) {
    __syncthreads();
#pragma unroll
    for (int it = 0; it < 4; it++) {
      int row = sr + it * 32;
      const float* src = X + (size_t)(m0 + row) * 512 + ks * 64 + sc;
      float4 a = *(const float4*)(src);
      float4 c = *(const float4*)(src + 4);
      unsigned short tmp[8] = {f2b(a.x), f2b(a.y), f2b(a.z), f2b(a.w),
                               f2b(c.x), f2b(c.y), f2b(c.z), f2b(c.w)};
      *(int4*)(lA + row * 72 + sc) = *(const int4*)tmp;
    }
    __syncthreads();
#pragma unroll
    for (int kk = 0; kk < 2; kk++) {
      short8 af[4], bf[4];
#pragma unroll
      for (int i = 0; i < 4; i++)
        af[i] = *(const short8*)(lA + (wr * 64 + i * 16 + lane16) * 72 + kk * 32 + quad * 8);
#pragma unroll
      for (int j = 0; j < 4; j++) {
        int F = (bn * 8 + wc * 4 + j) * 16 + ks * 2 + kk;
        bf[j] = *(const short8*)(Wp + (size_t)(F * 64 + l) * 8);
      }
#pragma unroll
      for (int i = 0; i < 4; i++)
#pragma unroll
        for (int j = 0; j < 4; j++)
          acc[i][j] = __builtin_amdgcn_mfma_f32_16x16x32_bf16(af[i], bf[j], acc[i][j], 0, 0, 0);
    }
  }
#pragma unroll
  for (int j = 0; j < 4; j++) {
    int n = bn * 128 + wc * 64 + j * 16 + lane16;
    float bj = bias[n];
#pragma unroll
    for (int i = 0; i < 4; i++)
#pragma unroll
      for (int r = 0; r < 4; r++) {
        int m = m0 + wr * 64 + i * 16 + quad * 4 + r;
        xp[(size_t)m * 4096 + n] = f2b(acc[i][j][r] + bj);
      }
  }
}

// ---- Phase C: persistent recurrent kernel — XCD-local teams ----
// 8 teams x 4 batches; team t formed at runtime from the 64 blocks that
// physically land on XCD t (HW_REG_XCC_ID claim via device atomics, with
// deterministic spill for imbalance). Intra-team h-exchange:
//   fast path : sc0 stores/loads meeting in the XCD's shared L2 (~200 cy)
//   shadow    : sc0sc1 dual-store at LLC (the 3-round-proven protocol);
//               consumers escalate after FASTP failed fast passes.
// h element = dword (h_bf16<<16 | step_tag); correctness rests ONLY on
// per-dword tag validation (no fences, any cache semantics -> at worst
// extra retries, never wrong data; shadow path bounds retries).
#define FASTP 4
__global__ __launch_bounds__(256, 2) void lstm_rec(
    const unsigned short* __restrict__ xp,
    const unsigned short* __restrict__ Up,
    unsigned* __restrict__ hbuf,         // [8][4][4][1024] dwords (fast)
    unsigned* __restrict__ shad,         // same layout (LLC shadow)
    unsigned* __restrict__ ctl,          // claim table
    float* __restrict__ out) {           // [32][512][1024] f32
  const int tid = threadIdx.x;
  const int l = tid & 63;
  const int kq = tid >> 6;           // wave = K-quarter
  const int quad = l >> 4, lane16 = l & 15;

  __shared__ float zbuf[2][4][4][4][17];   // [p][kq][gate][batch][col]
  __shared__ int sh_tr[2];

  // ---- runtime XCD claim: team = my physical XCD ----
  if (tid == 0) {
    unsigned xcc;
    asm volatile("s_getreg_b32 %0, hwreg(HW_REG_XCC_ID)" : "=s"(xcc));
    xcc &= 7u;
    int team, role;
    int slot = (int)atomicAdd(&ctl[xcc], 1u);
    if (slot < 64) { team = (int)xcc; role = slot; }
    else { role = (int)atomicAdd(&ctl[8], 1u); team = -1; }
    __threadfence();
    atomicAdd(&ctl[9], 1u);
    if (team < 0) {
      // wait for all 512 blocks to check in, then take a deficit slot
      while (atomicAdd(&ctl[9], 0u) < 512u) __builtin_amdgcn_s_sleep(8);
      __threadfence();
      int idx = role;
      for (int tt = 0; tt < 8; tt++) {
        int cl = (int)atomicAdd(&ctl[tt], 0u);
        int have = cl > 64 ? 64 : cl;
        int deficit = 64 - have;
        if (idx < deficit) { team = tt; role = have + idx; break; }
        idx -= deficit;
      }
    }
    sh_tr[0] = team; sh_tr[1] = role;
  }
  __syncthreads();
  const int team = sh_tr[0];
  const int cg = sh_tr[1];              // h-col group 0..63

  // preload B fragments (U slice) into registers: 4 gates x 8 k-frags x 16B
  short8 bfr[4][8];
#pragma unroll
  for (int g = 0; g < 4; g++)
#pragma unroll
    for (int kk = 0; kk < 8; kk++) {
      int F = ((cg * 4 + kq) * 4 + g) * 8 + kk;
      bfr[g][kk] = *(const short8*)(Up + (size_t)(F * 64 + l) * 8);
    }

  // consumer lane address core (team base + batch row + k-quarter + quad)
  const unsigned tbase = (unsigned)team * 16384u;
  const unsigned rowq = (unsigned)(lane16 & 3) * 1024u +
                        (unsigned)kq * 256u + (unsigned)quad * 8u;

  // elementwise ownership: tid<64 -> (batch bl, col jj)
  const int bl = tid >> 4;               // 0..3 (valid when tid<64)
  const int jj = tid & 15;
  const int bglob = team * 4 + bl;
  const unsigned stoff = (unsigned)bl * 1024u + (unsigned)cg * 16u + (unsigned)jj;

  float c_st = 0.0f;
  const unsigned short* xpbase = xp + (size_t)bglob * T_SZ * 4096 +
                                 (size_t)cg * 16 + jj;
  unsigned short xr0 = 0, xr1 = 0, xr2 = 0, xr3 = 0;
  if (tid < 64) {
    xr0 = xpbase[0];
    xr1 = xpbase[1024];
    xr2 = xpbase[2048];
    xr3 = xpbase[3072];
  }

#pragma unroll 1
  for (int t = 0; t < T_SZ; t++) {
    // ---- consume h(t): L2-local fast passes, shadow escalation ----
    const unsigned tag = (unsigned)t;
    const unsigned* hf = hbuf + tbase + (unsigned)(t & 3) * 4096u + rowq;
    const unsigned* hs = shad + tbase + (unsigned)(t & 3) * 4096u + rowq;
    short8 af[8];
    unsigned pend = 0xFFu;                       // wave-uniform frag bitmask
    int pass = 0;
    while (pend) {
      u32x4 ra[8], rb[8];
      if (pass < FASTP) {
#pragma unroll
        for (int f = 0; f < 8; f++) {
          if (pend & (1u << f)) {
            const unsigned* p = hf + f * 32;
            asm volatile("global_load_dwordx4 %0, %1, off sc0"
                         : "=v"(ra[f]) : "v"(p));
            asm volatile("global_load_dwordx4 %0, %1, off offset:16 sc0"
                         : "=v"(rb[f]) : "v"(p));
          }
        }
      } else {
#pragma unroll
        for (int f = 0; f < 8; f++) {
          if (pend & (1u << f)) {
            const unsigned* p = hs + f * 32;
            asm volatile("global_load_dwordx4 %0, %1, off sc0 sc1"
                         : "=v"(ra[f]) : "v"(p));
            asm volatile("global_load_dwordx4 %0, %1, off offset:16 sc0 sc1"
                         : "=v"(rb[f]) : "v"(p));
          }
        }
      }
      asm volatile("s_waitcnt vmcnt(0)" ::: "memory");
      __builtin_amdgcn_sched_barrier(0);
      unsigned np = pend;
#pragma unroll
      for (int f = 0; f < 8; f++) {
        if (pend & (1u << f)) {
          u32x4 a = ra[f], b = rb[f];
          unsigned bad = ((a[0] ^ tag) | (a[1] ^ tag) | (a[2] ^ tag) | (a[3] ^ tag) |
                          (b[0] ^ tag) | (b[1] ^ tag) | (b[2] ^ tag) | (b[3] ^ tag)) & 0xFFFFu;
          if (__ballot(bad != 0u) == 0ull) {
            np &= ~(1u << f);
            u32x4 v = {(a[0] >> 16) | (a[1] & 0xFFFF0000u),
                       (a[2] >> 16) | (a[3] & 0xFFFF0000u),
                       (b[0] >> 16) | (b[1] & 0xFFFF0000u),
                       (b[2] >> 16) | (b[3] & 0xFFFF0000u)};
            af[f] = __builtin_bit_cast(short8, v);
          }
        }
      }
      pend = np;
      pass++;
      if (pend && pass >= FASTP) __builtin_amdgcn_s_sleep(1);
    }

    // ---- z partial GEMM: wave kq covers k in [kq*256, kq*256+256) ----
    // A rows r hold batch (r&3) (4x duplicated) -> D rows 0..3 are the
    // real per-batch gate partials; quad 0 stores them.
    f32x4 acc[4];
#pragma unroll
    for (int g = 0; g < 4; g++) acc[g] = (f32x4){0.f, 0.f, 0.f, 0.f};
#pragma unroll
    for (int kk = 0; kk < 8; kk++) {
#pragma unroll
      for (int g = 0; g < 4; g++)
        acc[g] = __builtin_amdgcn_mfma_f32_16x16x32_bf16(af[kk], bfr[g][kk], acc[g], 0, 0, 0);
    }
    const int p = t & 1;
    if (quad == 0) {
#pragma unroll
      for (int g = 0; g < 4; g++)
#pragma unroll
        for (int r = 0; r < 4; r++)
          zbuf[p][kq][g][r][lane16] = acc[g][r];
    }
    __syncthreads();                 // the ONLY barrier per step

    if (tid < 64) {
      // ---- elementwise: thread -> (batch bl, h-col jj) ----
      float z0 = zbuf[p][0][0][bl][jj] + zbuf[p][1][0][bl][jj] + zbuf[p][2][0][bl][jj] + zbuf[p][3][0][bl][jj] + b2f(xr0);
      float z1 = zbuf[p][0][1][bl][jj] + zbuf[p][1][1][bl][jj] + zbuf[p][2][1][bl][jj] + zbuf[p][3][1][bl][jj] + b2f(xr1);
      float z2 = zbuf[p][0][2][bl][jj] + zbuf[p][1][2][bl][jj] + zbuf[p][2][2][bl][jj] + zbuf[p][3][2][bl][jj] + b2f(xr2);
      float z3 = zbuf[p][0][3][bl][jj] + zbuf[p][1][3][bl][jj] + zbuf[p][2][3][bl][jj] + zbuf[p][3][3][bl][jj] + b2f(xr3);
      float ig = sigm(z0);
      float fg = sigm(z1);
      float gg = tanh_f(z2);
      float og = sigm(z3);
      c_st = fg * c_st + ig * gg;
      float h = og * tanh_f(c_st);

      // ---- publish h(t+1): fast (L2) + shadow (LLC), tagged dwords ----
      unsigned tagged = ((unsigned)f2b(h) << 16) | (unsigned)(t + 1);
      unsigned hoff = tbase + (unsigned)((t + 1) & 3) * 4096u + stoff;
      const unsigned* pf = hbuf + hoff;
      const unsigned* ps = shad + hoff;
      asm volatile("global_store_dword %0, %1, off sc0"
                   :: "v"(pf), "v"(tagged) : "memory");
      asm volatile("global_store_dword %0, %1, off sc0 sc1"
                   :: "v"(ps), "v"(tagged) : "memory");

      // tail: out store + xp(t+1) prefetch
      out[((size_t)bglob * T_SZ + t) * 1024 + cg * 16 + jj] = h;
      int tn = (t + 1 < T_SZ) ? t + 1 : t;
      const unsigned short* xpn = xpbase + (size_t)tn * 4096;
      xr0 = xpn[0];
      xr1 = xpn[1024];
      xr2 = xpn[2048];
      xr3 = xpn[3072];
    }
  }
}

extern "C" void kernel_launch(void* const* d_in, const int* in_sizes, int n_in,
                              void* d_out, int out_size, void* d_ws, size_t ws_size,
                              hipStream_t stream) {
  const float* X    = (const float*)d_in[0];  // [32][512][512]  f32
  const float* W    = (const float*)d_in[1];  // [512][4096]     f32
  const float* U    = (const float*)d_in[2];  // [1024][4096]    f32
  const float* bias = (const float*)d_in[3];  // [4096]          f32
  float* out = (float*)d_out;                 // [32][512][1024] f32

  char* ws = (char*)d_ws;
  unsigned short* xp   = (unsigned short*)(ws + XP_OFF);
  unsigned short* Up   = (unsigned short*)(ws + UPERM_OFF);
  unsigned short* Wp   = (unsigned short*)(ws + WPERM_OFF);
  unsigned*       hbuf = (unsigned*)(ws + HBUF_OFF);
  unsigned*       shad = (unsigned*)(ws + SHAD_OFF);
  unsigned*       ctl  = (unsigned*)(ws + CTL_OFF);

  hipLaunchKernelGGL(permute_U, dim3(2048), dim3(256), 0, stream, U, Up);
  hipLaunchKernelGGL(permute_W, dim3(1024), dim3(256), 0, stream, W, Wp);
  hipLaunchKernelGGL(init_hbuf, dim3(1025), dim3(256), 0, stream, hbuf, shad, ctl);
  hipLaunchKernelGGL(xproj_gemm, dim3(32, 128), dim3(256), 0, stream, X, Wp, bias, xp);
  hipLaunchKernelGGL(lstm_rec, dim3(512), dim3(256), 0, stream, xp, Up, hbuf, shad, ctl, out);
}

// Round 10
// 4021.640 us; speedup vs baseline: 3.3541x; 3.3541x over previous
//
#include <hip/hip_runtime.h>
#include <stdint.h>

typedef __attribute__((ext_vector_type(8))) short short8;
typedef __attribute__((ext_vector_type(4))) float f32x4;
typedef __attribute__((ext_vector_type(4))) unsigned u32x4;

#define T_SZ 512

// ws layout (bytes)
#define XP_OFF    0ull                 // xp (bf16): 16384*4096*2 = 134217728
#define UPERM_OFF 134217728ull         // Uperm (bf16): 8 MB
#define WPERM_OFF 142606336ull         // Wperm (bf16): 4 MB
#define HBUF_OFF  146800640ull         // hbuf: 4 slabs x 32 x 1024 dwords = 512 KB

static __device__ __forceinline__ float b2f(unsigned short u) {
  unsigned v = ((unsigned)u) << 16;
  return __builtin_bit_cast(float, v);
}
static __device__ __forceinline__ unsigned short f2b(float f) {
  unsigned u = __builtin_bit_cast(unsigned, f);
  u += 0x7fffu + ((u >> 16) & 1u);   // RNE
  return (unsigned short)(u >> 16);
}
static __device__ __forceinline__ float sigm(float x) {
  return 1.0f / (1.0f + __expf(-x));
}
static __device__ __forceinline__ float tanh_f(float x) {
  return 1.0f - 2.0f / (__expf(2.0f * x) + 1.0f);
}

// ---- one-time permutation of U (f32 -> bf16) into MFMA B-fragment layout ----
__global__ void permute_U(const float* __restrict__ U, unsigned short* __restrict__ Up) {
  int t = blockIdx.x * 256 + threadIdx.x;        // 524288 threads
  int l = t & 63;
  int F = t >> 6;                                 // 8192 frags
  int kk = F & 7, g = (F >> 3) & 3, kq = (F >> 5) & 3, cg = F >> 7;
  int k0 = kq * 256 + kk * 32 + (l >> 4) * 8;
  int n  = g * 1024 + cg * 16 + (l & 15);
  unsigned short v[8];
#pragma unroll
  for (int j = 0; j < 8; j++) v[j] = f2b(U[(size_t)(k0 + j) * 4096 + n]);
  unsigned short* dst = Up + (size_t)t * 8;
#pragma unroll
  for (int j = 0; j < 8; j++) dst[j] = v[j];
}

__global__ void permute_W(const float* __restrict__ W, unsigned short* __restrict__ Wp) {
  int t = blockIdx.x * 256 + threadIdx.x;        // 262144 threads
  int l = t & 63;
  int F = t >> 6;                                 // 4096 frags
  int kk = F & 15, nt = F >> 4;
  int k0 = kk * 32 + (l >> 4) * 8;
  int n  = nt * 16 + (l & 15);
  unsigned short v[8];
#pragma unroll
  for (int j = 0; j < 8; j++) v[j] = f2b(W[(size_t)(k0 + j) * 4096 + n]);
  unsigned short* dst = Wp + (size_t)t * 8;
#pragma unroll
  for (int j = 0; j < 8; j++) dst[j] = v[j];
}

// hbuf: 4 slabs x 32768 dwords. slab 0 = (h=0, tag=0); slabs 1..3 = tag 0xFFFF.
__global__ void init_hbuf(unsigned* __restrict__ hbuf) {
  int t = blockIdx.x * 256 + threadIdx.x;        // 131072 threads
  hbuf[t] = (t < 32768) ? 0u : 0xFFFFu;
}

// ---- Phase B: xp[m][n] = X[m][:] @ W[:][n] + b[n], M=16384 N=4096 K=512 ----
__global__ __launch_bounds__(256) void xproj_gemm(
    const float* __restrict__ X,
    const unsigned short* __restrict__ Wp,
    const float* __restrict__ bias,
    unsigned short* __restrict__ xp) {
  const int tid = threadIdx.x;
  const int l = tid & 63;
  const int w = tid >> 6;
  const int wr = w >> 1, wc = w & 1;
  const int bn = blockIdx.x;   // 32
  const int bm = blockIdx.y;   // 128
  const int quad = l >> 4, lane16 = l & 15;
  __shared__ unsigned short lA[128 * 72];

  f32x4 acc[4][4];
#pragma unroll
  for (int i = 0; i < 4; i++)
#pragma unroll
    for (int j = 0; j < 4; j++) acc[i][j] = (f32x4){0.f, 0.f, 0.f, 0.f};

  const int m0 = bm * 128;
  const int sr = tid >> 3;
  const int sc = (tid & 7) * 8;

  for (int ks = 0; ks < 8; ks++) {
    __syncthreads();
#pragma unroll
    for (int it = 0; it < 4; it++) {
      int row = sr + it * 32;
      const float* src = X + (size_t)(m0 + row) * 512 + ks * 64 + sc;
      float4 a = *(const float4*)(src);
      float4 c = *(const float4*)(src + 4);
      unsigned short tmp[8] = {f2b(a.x), f2b(a.y), f2b(a.z), f2b(a.w),
                               f2b(c.x), f2b(c.y), f2b(c.z), f2b(c.w)};
      *(int4*)(lA + row * 72 + sc) = *(const int4*)tmp;
    }
    __syncthreads();
#pragma unroll
    for (int kk = 0; kk < 2; kk++) {
      short8 af[4], bf[4];
#pragma unroll
      for (int i = 0; i < 4; i++)
        af[i] = *(const short8*)(lA + (wr * 64 + i * 16 + lane16) * 72 + kk * 32 + quad * 8);
#pragma unroll
      for (int j = 0; j < 4; j++) {
        int F = (bn * 8 + wc * 4 + j) * 16 + ks * 2 + kk;
        bf[j] = *(const short8*)(Wp + (size_t)(F * 64 + l) * 8);
      }
#pragma unroll
      for (int i = 0; i < 4; i++)
#pragma unroll
        for (int j = 0; j < 4; j++)
          acc[i][j] = __builtin_amdgcn_mfma_f32_16x16x32_bf16(af[i], bf[j], acc[i][j], 0, 0, 0);
    }
  }
#pragma unroll
  for (int j = 0; j < 4; j++) {
    int n = bn * 128 + wc * 64 + j * 16 + lane16;
    float bj = bias[n];
#pragma unroll
    for (int i = 0; i < 4; i++)
#pragma unroll
      for (int r = 0; r < 4; r++) {
        int m = m0 + wr * 64 + i * 16 + quad * 4 + r;
        xp[(size_t)m * 4096 + n] = f2b(acc[i][j][r] + bj);
      }
  }
}

// ---- Phase C: persistent recurrent kernel — dual-chain latency hiding ----
// 64 blocks x 256 thr. Each block owns 16 h-cols (cg) for BOTH batch-halves
// and alternates the two INDEPENDENT recurrent chains each step:
//   validate A -> compute A -> store A -> validate B -> compute B -> store B
// While chain A's tagged store drains to the LLC (visibility latency ~2-3us,
// the r1-r3 invariant bottleneck), chain B's validate+MFMA+reduce runs ->
// the drain is hidden behind useful work. U fragments are shared between
// chains (same columns), so VGPR cost is unchanged. Transport protocol is
// byte-identical to r1/r3 per chain: dword = (h_bf16<<16 | step_tag),
// relaxed agent store, pipelined sc0sc1 dwordx4 spin + single wait + tag
// validation. Slab distance-4 reuse safe per chain (program order makes
// cross-chain reuse safe: completing A(t-1) implies B(t-2) complete).
__global__ __launch_bounds__(256, 1) void lstm_rec(
    const unsigned short* __restrict__ xp,
    const unsigned short* __restrict__ Up,
    unsigned* __restrict__ hbuf,         // [4][32][1024] dwords
    float* __restrict__ out) {           // [32][512][1024] f32
  const int tid = threadIdx.x;
  const int l = tid & 63;
  const int kq = tid >> 6;           // wave = K-quarter
  const int cg = blockIdx.x;         // 0..63 h-col group
  const int quad = l >> 4, lane16 = l & 15;

  // stride 20: 4-quad write pattern tiles 32 banks 2-way (free) [r3]
  __shared__ float zbuf[2][4][4][16][20];      // [chain][kq][gate][b][col]

  // preload B fragments (U slice) into registers: 4 gates x 8 k-frags x 16B
  short8 bfr[4][8];
#pragma unroll
  for (int g = 0; g < 4; g++)
#pragma unroll
    for (int kk = 0; kk < 8; kk++) {
      int F = ((cg * 4 + kq) * 4 + g) * 8 + kk;
      bfr[g][kk] = *(const short8*)(Up + (size_t)(F * 64 + l) * 8);
    }

  const int bl = tid >> 4;           // 0..15 batch within half
  const int jj = tid & 15;

  unsigned rowoff[2], stoff[2];
  const unsigned short* xpb[2];
  unsigned short xr[2][4];
  float cst[2] = {0.0f, 0.0f};
#pragma unroll
  for (int c = 0; c < 2; c++) {
    // consumer base: row = batch (c*16+lane16), k-quarter kq (dword units)
    rowoff[c] = (unsigned)(c * 16 + lane16) * 1024u + (unsigned)kq * 256u;
    // producer store slot (dword units, within slab)
    stoff[c] = (unsigned)(c * 16 + bl) * 1024u + (unsigned)cg * 16u + (unsigned)jj;
    xpb[c] = xp + (size_t)(c * 16 + bl) * T_SZ * 4096 + (size_t)cg * 16 + jj;
    xr[c][0] = xpb[c][0];
    xr[c][1] = xpb[c][1024];
    xr[c][2] = xpb[c][2048];
    xr[c][3] = xpb[c][3072];
  }

#pragma unroll 1
  for (int t = 0; t < T_SZ; t++) {
    const unsigned tag = (unsigned)t;
#pragma unroll
    for (int c = 0; c < 2; c++) {
      // ---- consume h_c(t): pipelined loads, single wait, tag-validate ----
      const unsigned* hb32 = hbuf + (size_t)(t & 3) * 32768 + rowoff[c];
      short8 af[8];
      unsigned pend = 0xFFu;                     // wave-uniform frag bitmask
      while (pend) {
        u32x4 ra[8], rb[8];
#pragma unroll
        for (int f = 0; f < 8; f++) {
          if (pend & (1u << f)) {
            const unsigned* p = hb32 + f * 32 + quad * 8;
            asm volatile("global_load_dwordx4 %0, %1, off sc0 sc1"
                         : "=v"(ra[f]) : "v"(p));
            asm volatile("global_load_dwordx4 %0, %1, off offset:16 sc0 sc1"
                         : "=v"(rb[f]) : "v"(p));
          }
        }
        asm volatile("s_waitcnt vmcnt(0)" ::: "memory");
        __builtin_amdgcn_sched_barrier(0);
        unsigned np = pend;
#pragma unroll
        for (int f = 0; f < 8; f++) {
          if (pend & (1u << f)) {
            u32x4 a = ra[f], b = rb[f];
            unsigned bad = ((a[0] ^ tag) | (a[1] ^ tag) | (a[2] ^ tag) | (a[3] ^ tag) |
                            (b[0] ^ tag) | (b[1] ^ tag) | (b[2] ^ tag) | (b[3] ^ tag)) & 0xFFFFu;
            if (__ballot(bad != 0u) == 0ull) {
              np &= ~(1u << f);
              u32x4 v = {(a[0] >> 16) | (a[1] & 0xFFFF0000u),
                         (a[2] >> 16) | (a[3] & 0xFFFF0000u),
                         (b[0] >> 16) | (b[1] & 0xFFFF0000u),
                         (b[2] >> 16) | (b[3] & 0xFFFF0000u)};
              af[f] = __builtin_bit_cast(short8, v);
            }
          }
        }
        pend = np;
        if (pend) __builtin_amdgcn_s_sleep(1);
      }

      // ---- z partial GEMM: wave kq covers k in [kq*256, kq*256+256) ----
      f32x4 acc[4];
#pragma unroll
      for (int g = 0; g < 4; g++) acc[g] = (f32x4){0.f, 0.f, 0.f, 0.f};
#pragma unroll
      for (int kk = 0; kk < 8; kk++) {
#pragma unroll
        for (int g = 0; g < 4; g++)
          acc[g] = __builtin_amdgcn_mfma_f32_16x16x32_bf16(af[kk], bfr[g][kk], acc[g], 0, 0, 0);
      }
#pragma unroll
      for (int g = 0; g < 4; g++)
#pragma unroll
        for (int r = 0; r < 4; r++)
          zbuf[c][kq][g][quad * 4 + r][lane16] = acc[g][r];
      __syncthreads();               // one barrier per chain per step

      // ---- elementwise: thread -> (batch c*16+bl, h-col jj) ----
      float z0 = zbuf[c][0][0][bl][jj] + zbuf[c][1][0][bl][jj] + zbuf[c][2][0][bl][jj] + zbuf[c][3][0][bl][jj] + b2f(xr[c][0]);
      float z1 = zbuf[c][0][1][bl][jj] + zbuf[c][1][1][bl][jj] + zbuf[c][2][1][bl][jj] + zbuf[c][3][1][bl][jj] + b2f(xr[c][1]);
      float z2 = zbuf[c][0][2][bl][jj] + zbuf[c][1][2][bl][jj] + zbuf[c][2][2][bl][jj] + zbuf[c][3][2][bl][jj] + b2f(xr[c][2]);
      float z3 = zbuf[c][0][3][bl][jj] + zbuf[c][1][3][bl][jj] + zbuf[c][2][3][bl][jj] + zbuf[c][3][3][bl][jj] + b2f(xr[c][3]);
      float ig = sigm(z0);
      float fg = sigm(z1);
      float gg = tanh_f(z2);
      float og = sigm(z3);
      cst[c] = fg * cst[c] + ig * gg;
      float h = og * tanh_f(cst[c]);

      // ---- publish h_c(t+1): tagged dword; drain hides under next chain ----
      unsigned tagged = ((unsigned)f2b(h) << 16) | (unsigned)(t + 1);
      __hip_atomic_store(hbuf + (size_t)((t + 1) & 3) * 32768 + stoff[c], tagged,
                         __ATOMIC_RELAXED, __HIP_MEMORY_SCOPE_AGENT);

      // tail: out store + xp_c(t+1) prefetch
      out[((size_t)(c * 16 + bl) * T_SZ + t) * 1024 + cg * 16 + jj] = h;
      int tn = (t + 1 < T_SZ) ? t + 1 : t;
      const unsigned short* xpn = xpb[c] + (size_t)tn * 4096;
      xr[c][0] = xpn[0];
      xr[c][1] = xpn[1024];
      xr[c][2] = xpn[2048];
      xr[c][3] = xpn[3072];
    }
  }
}

extern "C" void kernel_launch(void* const* d_in, const int* in_sizes, int n_in,
                              void* d_out, int out_size, void* d_ws, size_t ws_size,
                              hipStream_t stream) {
  const float* X    = (const float*)d_in[0];  // [32][512][512]  f32
  const float* W    = (const float*)d_in[1];  // [512][4096]     f32
  const float* U    = (const float*)d_in[2];  // [1024][4096]    f32
  const float* bias = (const float*)d_in[3];  // [4096]          f32
  float* out = (float*)d_out;                 // [32][512][1024] f32

  char* ws = (char*)d_ws;
  unsigned short* xp   = (unsigned short*)(ws + XP_OFF);
  unsigned short* Up   = (unsigned short*)(ws + UPERM_OFF);
  unsigned short* Wp   = (unsigned short*)(ws + WPERM_OFF);
  unsigned*       hbuf = (unsigned*)(ws + HBUF_OFF);

  hipLaunchKernelGGL(permute_U, dim3(2048), dim3(256), 0, stream, U, Up);
  hipLaunchKernelGGL(permute_W, dim3(1024), dim3(256), 0, stream, W, Wp);
  hipLaunchKernelGGL(init_hbuf, dim3(512), dim3(256), 0, stream, hbuf);
  hipLaunchKernelGGL(xproj_gemm, dim3(32, 128), dim3(256), 0, stream, X, Wp, bias, xp);
  hipLaunchKernelGGL(lstm_rec, dim3(64), dim3(256), 0, stream, xp, Up, hbuf, out);
}

// Round 12
// 3190.670 us; speedup vs baseline: 4.2277x; 1.2604x over previous
//
#include <hip/hip_runtime.h>
#include <stdint.h>

typedef __attribute__((ext_vector_type(8))) short short8;
typedef __attribute__((ext_vector_type(4))) float f32x4;
typedef __attribute__((ext_vector_type(4))) unsigned u32x4;

#define T_SZ 512

// ws layout (bytes)
#define XP_OFF    0ull                 // xp (bf16): 16384*4096*2 = 134217728
#define UPERM_OFF 134217728ull         // Uperm (bf16): 8 MB
#define WPERM_OFF 142606336ull         // Wperm (bf16): 4 MB
#define HBUF_OFF  146800640ull         // hbuf: 4 slabs x 32 x 1024 dwords = 512 KB
#define FLAGS_OFF 147324928ull         // flags: 2 teams x 64 producers dwords

static __device__ __forceinline__ float b2f(unsigned short u) {
  unsigned v = ((unsigned)u) << 16;
  return __builtin_bit_cast(float, v);
}
static __device__ __forceinline__ unsigned short f2b(float f) {
  unsigned u = __builtin_bit_cast(unsigned, f);
  u += 0x7fffu + ((u >> 16) & 1u);   // RNE
  return (unsigned short)(u >> 16);
}
static __device__ __forceinline__ float sigm(float x) {
  return 1.0f / (1.0f + __expf(-x));
}
static __device__ __forceinline__ float tanh_f(float x) {
  return 1.0f - 2.0f / (__expf(2.0f * x) + 1.0f);
}

// ---- one-time permutation of U (f32 -> bf16) into MFMA B-fragment layout ----
__global__ void permute_U(const float* __restrict__ U, unsigned short* __restrict__ Up) {
  int t = blockIdx.x * 256 + threadIdx.x;        // 524288 threads
  int l = t & 63;
  int F = t >> 6;                                 // 8192 frags
  int kk = F & 7, g = (F >> 3) & 3, kq = (F >> 5) & 3, cg = F >> 7;
  int k0 = kq * 256 + kk * 32 + (l >> 4) * 8;
  int n  = g * 1024 + cg * 16 + (l & 15);
  unsigned short v[8];
#pragma unroll
  for (int j = 0; j < 8; j++) v[j] = f2b(U[(size_t)(k0 + j) * 4096 + n]);
  unsigned short* dst = Up + (size_t)t * 8;
#pragma unroll
  for (int j = 0; j < 8; j++) dst[j] = v[j];
}

__global__ void permute_W(const float* __restrict__ W, unsigned short* __restrict__ Wp) {
  int t = blockIdx.x * 256 + threadIdx.x;        // 262144 threads
  int l = t & 63;
  int F = t >> 6;                                 // 4096 frags
  int kk = F & 15, nt = F >> 4;
  int k0 = kk * 32 + (l >> 4) * 8;
  int n  = nt * 16 + (l & 15);
  unsigned short v[8];
#pragma unroll
  for (int j = 0; j < 8; j++) v[j] = f2b(W[(size_t)(k0 + j) * 4096 + n]);
  unsigned short* dst = Wp + (size_t)t * 8;
#pragma unroll
  for (int j = 0; j < 8; j++) dst[j] = v[j];
}

// hbuf: 4 slabs x 32768 dwords. slab 0 = (h=0, tag=0); slabs 1..3 = tag 0xFFFF.
// flags: 128 dwords = latest step published by each producer block, init 0.
__global__ void init_hbuf(unsigned* __restrict__ hbuf, unsigned* __restrict__ flags) {
  int t = blockIdx.x * 256 + threadIdx.x;        // 513*256 threads
  if (t < 131072) hbuf[t] = (t < 32768) ? 0u : 0xFFFFu;
  else if (t < 131072 + 128) flags[t - 131072] = 0u;
}

// ---- Phase B: xp[m][n] = X[m][:] @ W[:][n] + b[n], M=16384 N=4096 K=512 ----
__global__ __launch_bounds__(256) void xproj_gemm(
    const float* __restrict__ X,
    const unsigned short* __restrict__ Wp,
    const float* __restrict__ bias,
    unsigned short* __restrict__ xp) {
  const int tid = threadIdx.x;
  const int l = tid & 63;
  const int w = tid >> 6;
  const int wr = w >> 1, wc = w & 1;
  const int bn = blockIdx.x;   // 32
  const int bm = blockIdx.y;   // 128
  const int quad = l >> 4, lane16 = l & 15;
  __shared__ unsigned short lA[128 * 72];

  f32x4 acc[4][4];
#pragma unroll
  for (int i = 0; i < 4; i++)
#pragma unroll
    for (int j = 0; j < 4; j++) acc[i][j] = (f32x4){0.f, 0.f, 0.f, 0.f};

  const int m0 = bm * 128;
  const int sr = tid >> 3;
  const int sc = (tid & 7) * 8;

  for (int ks = 0; ks < 8; ks++) {
    __syncthreads();
#pragma unroll
    for (int it = 0; it < 4; it++) {
      int row = sr + it * 32;
      const float* src = X + (size_t)(m0 + row) * 512 + ks * 64 + sc;
      float4 a = *(const float4*)(src);
      float4 c = *(const float4*)(src + 4);
      unsigned short tmp[8] = {f2b(a.x), f2b(a.y), f2b(a.z), f2b(a.w),
                               f2b(c.x), f2b(c.y), f2b(c.z), f2b(c.w)};
      *(int4*)(lA + row * 72 + sc) = *(const int4*)tmp;
    }
    __syncthreads();
#pragma unroll
    for (int kk = 0; kk < 2; kk++) {
      short8 af[4], bf[4];
#pragma unroll
      for (int i = 0; i < 4; i++)
        af[i] = *(const short8*)(lA + (wr * 64 + i * 16 + lane16) * 72 + kk * 32 + quad * 8);
#pragma unroll
      for (int j = 0; j < 4; j++) {
        int F = (bn * 8 + wc * 4 + j) * 16 + ks * 2 + kk;
        bf[j] = *(const short8*)(Wp + (size_t)(F * 64 + l) * 8);
      }
#pragma unroll
      for (int i = 0; i < 4; i++)
#pragma unroll
        for (int j = 0; j < 4; j++)
          acc[i][j] = __builtin_amdgcn_mfma_f32_16x16x32_bf16(af[i], bf[j], acc[i][j], 0, 0, 0);
    }
  }
#pragma unroll
  for (int j = 0; j < 4; j++) {
    int n = bn * 128 + wc * 64 + j * 16 + lane16;
    float bj = bias[n];
#pragma unroll
    for (int i = 0; i < 4; i++)
#pragma unroll
      for (int r = 0; r < 4; r++) {
        int m = m0 + wr * 64 + i * 16 + quad * 4 + r;
        xp[(size_t)m * 4096 + n] = f2b(acc[i][j][r] + bj);
      }
  }
}

// ---- Phase C: persistent recurrent kernel — pre-issued speculative pass ----
// r3 topology (128 blocks x 256 thr, flag-gated retry, stride-20 zbuf) plus:
//  (1) pass-1 loads for step t+1 are ISSUED right after publishing own
//      h(t+1) — they fly during the elementwise tail and other producers'
//      publishes, so at t+1's validate the first pass is already resident
//      (free). Failures fall into the flag-gated retry exactly as r3.
//  (2) publish via global_atomic_swap (no return): executed at the device
//      coherence point — removes any lazy-writeback drain component.
// Correctness unchanged: per-dword tag validation is the sole authority;
// speculatively reading a slab that is still being written just yields
// stale tags and a retry. Slab distance-4 reuse argument as before.
__global__ __launch_bounds__(256, 1) void lstm_rec(
    const unsigned short* __restrict__ xp,
    const unsigned short* __restrict__ Up,
    unsigned* __restrict__ hbuf,         // [4][32][1024] dwords
    unsigned* __restrict__ flags,        // [2][64] dwords
    float* __restrict__ out) {           // [32][512][1024] f32
  const int tid = threadIdx.x;
  const int l = tid & 63;
  const int kq = tid >> 6;           // wave = K-quarter
  const int bid = blockIdx.x;        // 0..127
  const int mh = bid >> 6;           // team (batch half)
  const int cg = bid & 63;           // h-col group
  const int quad = l >> 4, lane16 = l & 15;

  // stride 20: 4-quad write pattern tiles 32 banks exactly 2-way (free)
  __shared__ float zbuf[2][4][4][16][20];      // [p][kq][gate][b][col]

  // preload B fragments (U slice) into registers: 4 gates x 8 k-frags x 16B
  short8 bfr[4][8];
#pragma unroll
  for (int g = 0; g < 4; g++)
#pragma unroll
    for (int kk = 0; kk < 8; kk++) {
      int F = ((cg * 4 + kq) * 4 + g) * 8 + kk;
      bfr[g][kk] = *(const short8*)(Up + (size_t)(F * 64 + l) * 8);
    }

  float c_st = 0.0f;
  const int bl = tid >> 4;           // 0..15
  const int jj = tid & 15;
  const int bglob = mh * 16 + bl;

  // consumer base: row = batch (mh*16+lane16), k-quarter kq (dword units)
  const unsigned rowoff = (unsigned)(mh * 16 + lane16) * 1024 + (unsigned)kq * 256;
  // producer store slot (dword units, within slab)
  const unsigned stoff = (unsigned)bglob * 1024 + (unsigned)cg * 16 + jj;
  // flag poll address: lane l watches producer cg=l of team mh
  const unsigned* flgp = flags + mh * 64 + l;
  // flag publish address (block-uniform)
  unsigned* flgst = flags + mh * 64 + cg;

  // xp(0) preload (normal cached; produced by earlier dispatch)
  const unsigned short* xpbase =
      xp + (size_t)bglob * T_SZ * 4096 + (size_t)cg * 16 + jj;
  unsigned short xr0 = xpbase[0];
  unsigned short xr1 = xpbase[1024];
  unsigned short xr2 = xpbase[2048];
  unsigned short xr3 = xpbase[3072];

  // pre-issue pass-1 for t=0 (slab 0 is pre-tagged by init -> will validate)
  u32x4 ra[8], rb[8];
  {
    const unsigned* hb0 = hbuf + rowoff;
#pragma unroll
    for (int f = 0; f < 8; f++) {
      const unsigned* p = hb0 + f * 32 + quad * 8;
      asm volatile("global_load_dwordx4 %0, %1, off sc0 sc1"
                   : "=v"(ra[f]) : "v"(p));
      asm volatile("global_load_dwordx4 %0, %1, off offset:16 sc0 sc1"
                   : "=v"(rb[f]) : "v"(p));
    }
  }

#pragma unroll 1
  for (int t = 0; t < T_SZ; t++) {
    // ---- consume h(t): validate pre-issued pass, flag-gated retry ----
    const unsigned tag = (unsigned)t;
    const unsigned* hb32 = hbuf + (size_t)(t & 3) * 32768 + rowoff;
    short8 af[8];
    unsigned pend = 0xFFu;                       // wave-uniform frag bitmask
    bool first = true;
    while (pend) {
      if (!first) {
        // cheap flag gate: one coalesced dword load per pass (256 B/wave)
        while (true) {
          unsigned fl;
          asm volatile("global_load_dword %0, %1, off sc0 sc1"
                       : "=v"(fl) : "v"(flgp));
          asm volatile("s_waitcnt vmcnt(0)" ::: "memory");
          __builtin_amdgcn_sched_barrier(0);
          if (__ballot(fl < tag) == 0ull) break;
          __builtin_amdgcn_s_sleep(1);
        }
        // re-issue only pending frags
#pragma unroll
        for (int f = 0; f < 8; f++) {
          if (pend & (1u << f)) {
            const unsigned* p = hb32 + f * 32 + quad * 8;
            asm volatile("global_load_dwordx4 %0, %1, off sc0 sc1"
                         : "=v"(ra[f]) : "v"(p));
            asm volatile("global_load_dwordx4 %0, %1, off offset:16 sc0 sc1"
                         : "=v"(rb[f]) : "v"(p));
          }
        }
      }
      asm volatile("s_waitcnt vmcnt(0)" ::: "memory");
      __builtin_amdgcn_sched_barrier(0);
      first = false;
      unsigned np = pend;
#pragma unroll
      for (int f = 0; f < 8; f++) {
        if (pend & (1u << f)) {
          u32x4 a = ra[f], b = rb[f];
          unsigned bad = ((a[0] ^ tag) | (a[1] ^ tag) | (a[2] ^ tag) | (a[3] ^ tag) |
                          (b[0] ^ tag) | (b[1] ^ tag) | (b[2] ^ tag) | (b[3] ^ tag)) & 0xFFFFu;
          if (__ballot(bad != 0u) == 0ull) {
            np &= ~(1u << f);
            u32x4 v = {(a[0] >> 16) | (a[1] & 0xFFFF0000u),
                       (a[2] >> 16) | (a[3] & 0xFFFF0000u),
                       (b[0] >> 16) | (b[1] & 0xFFFF0000u),
                       (b[2] >> 16) | (b[3] & 0xFFFF0000u)};
            af[f] = __builtin_bit_cast(short8, v);
          }
        }
      }
      pend = np;
    }

    // ---- z partial GEMM: wave kq covers k in [kq*256, kq*256+256) ----
    f32x4 acc[4];
#pragma unroll
    for (int g = 0; g < 4; g++) acc[g] = (f32x4){0.f, 0.f, 0.f, 0.f};
#pragma unroll
    for (int kk = 0; kk < 8; kk++) {
#pragma unroll
      for (int g = 0; g < 4; g++)
        acc[g] = __builtin_amdgcn_mfma_f32_16x16x32_bf16(af[kk], bfr[g][kk], acc[g], 0, 0, 0);
    }
    const int p = t & 1;
#pragma unroll
    for (int g = 0; g < 4; g++)
#pragma unroll
      for (int r = 0; r < 4; r++)
        zbuf[p][kq][g][quad * 4 + r][lane16] = acc[g][r];
    __syncthreads();                 // the ONLY barrier per step

    // ---- elementwise: thread -> (batch bl, h-col jj) ----
    float z0 = zbuf[p][0][0][bl][jj] + zbuf[p][1][0][bl][jj] + zbuf[p][2][0][bl][jj] + zbuf[p][3][0][bl][jj] + b2f(xr0);
    float z1 = zbuf[p][0][1][bl][jj] + zbuf[p][1][1][bl][jj] + zbuf[p][2][1][bl][jj] + zbuf[p][3][1][bl][jj] + b2f(xr1);
    float z2 = zbuf[p][0][2][bl][jj] + zbuf[p][1][2][bl][jj] + zbuf[p][2][2][bl][jj] + zbuf[p][3][2][bl][jj] + b2f(xr2);
    float z3 = zbuf[p][0][3][bl][jj] + zbuf[p][1][3][bl][jj] + zbuf[p][2][3][bl][jj] + zbuf[p][3][3][bl][jj] + b2f(xr3);
    float ig = sigm(z0);
    float fg = sigm(z1);
    float gg = tanh_f(z2);
    float og = sigm(z3);
    c_st = fg * c_st + ig * gg;
    float h = og * tanh_f(c_st);

    // ---- publish h(t+1): atomic swap executes at coherence point ----
    unsigned tagged = ((unsigned)f2b(h) << 16) | (unsigned)(t + 1);
    {
      unsigned* hp = hbuf + (size_t)((t + 1) & 3) * 32768 + stoff;
      asm volatile("global_atomic_swap %0, %1, off"
                   :: "v"(hp), "v"(tagged) : "memory");
    }
    // flag hint: this block has published step t+1 (unordered; tags validate)
    if (tid == 0)
      __hip_atomic_store(flgst, (unsigned)(t + 1),
                         __ATOMIC_RELAXED, __HIP_MEMORY_SCOPE_AGENT);

    // ---- pre-issue pass-1 loads for step t+1 (overlap with tail) ----
    {
      const unsigned* hbn = hbuf + (size_t)((t + 1) & 3) * 32768 + rowoff;
#pragma unroll
      for (int f = 0; f < 8; f++) {
        const unsigned* pp = hbn + f * 32 + quad * 8;
        asm volatile("global_load_dwordx4 %0, %1, off sc0 sc1"
                     : "=v"(ra[f]) : "v"(pp));
        asm volatile("global_load_dwordx4 %0, %1, off offset:16 sc0 sc1"
                     : "=v"(rb[f]) : "v"(pp));
      }
    }

    // tail (overlaps other blocks' progress): out store + xp(t+1) prefetch
    out[((size_t)bglob * T_SZ + t) * 1024 + cg * 16 + jj] = h;
    {
      int tn = (t + 1 < T_SZ) ? t + 1 : t;
      const unsigned short* xpn = xpbase + (size_t)tn * 4096;
      xr0 = xpn[0];
      xr1 = xpn[1024];
      xr2 = xpn[2048];
      xr3 = xpn[3072];
    }
  }
}

extern "C" void kernel_launch(void* const* d_in, const int* in_sizes, int n_in,
                              void* d_out, int out_size, void* d_ws, size_t ws_size,
                              hipStream_t stream) {
  const float* X    = (const float*)d_in[0];  // [32][512][512]  f32
  const float* W    = (const float*)d_in[1];  // [512][4096]     f32
  const float* U    = (const float*)d_in[2];  // [1024][4096]    f32
  const float* bias = (const float*)d_in[3];  // [4096]          f32
  float* out = (float*)d_out;                 // [32][512][1024] f32

  char* ws = (char*)d_ws;
  unsigned short* xp    = (unsigned short*)(ws + XP_OFF);
  unsigned short* Up    = (unsigned short*)(ws + UPERM_OFF);
  unsigned short* Wp    = (unsigned short*)(ws + WPERM_OFF);
  unsigned*       hbuf  = (unsigned*)(ws + HBUF_OFF);
  unsigned*       flags = (unsigned*)(ws + FLAGS_OFF);

  hipLaunchKernelGGL(permute_U, dim3(2048), dim3(256), 0, stream, U, Up);
  hipLaunchKernelGGL(permute_W, dim3(1024), dim3(256), 0, stream, W, Wp);
  hipLaunchKernelGGL(init_hbuf, dim3(513), dim3(256), 0, stream, hbuf, flags);
  hipLaunchKernelGGL(xproj_gemm, dim3(32, 128), dim3(256), 0, stream, X, Wp, bias, xp);
  hipLaunchKernelGGL(lstm_rec, dim3(128), dim3(256), 0, stream, xp, Up, hbuf, flags, out);
}

// Round 13
// 2993.848 us; speedup vs baseline: 4.5056x; 1.0657x over previous
//
#include <hip/hip_runtime.h>
#include <stdint.h>

typedef __attribute__((ext_vector_type(8))) short short8;
typedef __attribute__((ext_vector_type(4))) float f32x4;
typedef __attribute__((ext_vector_type(4))) unsigned u32x4;

#define T_SZ 512

// ws layout (bytes)
#define XP_OFF    0ull                 // xp (bf16): 16384*4096*2 = 134217728
#define UPERM_OFF 134217728ull         // Uperm (bf16): 8 MB
#define WPERM_OFF 142606336ull         // Wperm (bf16): 4 MB
#define HBUF_OFF  146800640ull         // hbuf: 4 slabs x 32 x 1024 dwords = 512 KB
#define FLAGS_OFF 147324928ull         // flags: 2 teams x 64 producers dwords

static __device__ __forceinline__ float b2f(unsigned short u) {
  unsigned v = ((unsigned)u) << 16;
  return __builtin_bit_cast(float, v);
}
static __device__ __forceinline__ unsigned short f2b(float f) {
  unsigned u = __builtin_bit_cast(unsigned, f);
  u += 0x7fffu + ((u >> 16) & 1u);   // RNE
  return (unsigned short)(u >> 16);
}
static __device__ __forceinline__ float sigm(float x) {
  return 1.0f / (1.0f + __expf(-x));
}
static __device__ __forceinline__ float tanh_f(float x) {
  return 1.0f - 2.0f / (__expf(2.0f * x) + 1.0f);
}

// ---- one-time permutation of U (f32 -> bf16) into MFMA B-fragment layout ----
__global__ void permute_U(const float* __restrict__ U, unsigned short* __restrict__ Up) {
  int t = blockIdx.x * 256 + threadIdx.x;        // 524288 threads
  int l = t & 63;
  int F = t >> 6;                                 // 8192 frags
  int kk = F & 7, g = (F >> 3) & 3, kq = (F >> 5) & 3, cg = F >> 7;
  int k0 = kq * 256 + kk * 32 + (l >> 4) * 8;
  int n  = g * 1024 + cg * 16 + (l & 15);
  unsigned short v[8];
#pragma unroll
  for (int j = 0; j < 8; j++) v[j] = f2b(U[(size_t)(k0 + j) * 4096 + n]);
  unsigned short* dst = Up + (size_t)t * 8;
#pragma unroll
  for (int j = 0; j < 8; j++) dst[j] = v[j];
}

__global__ void permute_W(const float* __restrict__ W, unsigned short* __restrict__ Wp) {
  int t = blockIdx.x * 256 + threadIdx.x;        // 262144 threads
  int l = t & 63;
  int F = t >> 6;                                 // 4096 frags
  int kk = F & 15, nt = F >> 4;
  int k0 = kk * 32 + (l >> 4) * 8;
  int n  = nt * 16 + (l & 15);
  unsigned short v[8];
#pragma unroll
  for (int j = 0; j < 8; j++) v[j] = f2b(W[(size_t)(k0 + j) * 4096 + n]);
  unsigned short* dst = Wp + (size_t)t * 8;
#pragma unroll
  for (int j = 0; j < 8; j++) dst[j] = v[j];
}

// hbuf: 4 slabs x 32768 dwords. slab 0 = (h=0, tag=0); slabs 1..3 = tag 0xFFFF.
// flags: 128 dwords = latest step published by each producer block, init 0.
__global__ void init_hbuf(unsigned* __restrict__ hbuf, unsigned* __restrict__ flags) {
  int t = blockIdx.x * 256 + threadIdx.x;        // 513*256 threads
  if (t < 131072) hbuf[t] = (t < 32768) ? 0u : 0xFFFFu;
  else if (t < 131072 + 128) flags[t - 131072] = 0u;
}

// ---- Phase B: xp[m][n] = X[m][:] @ W[:][n] + b[n], M=16384 N=4096 K=512 ----
__global__ __launch_bounds__(256) void xproj_gemm(
    const float* __restrict__ X,
    const unsigned short* __restrict__ Wp,
    const float* __restrict__ bias,
    unsigned short* __restrict__ xp) {
  const int tid = threadIdx.x;
  const int l = tid & 63;
  const int w = tid >> 6;
  const int wr = w >> 1, wc = w & 1;
  const int bn = blockIdx.x;   // 32
  const int bm = blockIdx.y;   // 128
  const int quad = l >> 4, lane16 = l & 15;
  __shared__ unsigned short lA[128 * 72];

  f32x4 acc[4][4];
#pragma unroll
  for (int i = 0; i < 4; i++)
#pragma unroll
    for (int j = 0; j < 4; j++) acc[i][j] = (f32x4){0.f, 0.f, 0.f, 0.f};

  const int m0 = bm * 128;
  const int sr = tid >> 3;
  const int sc = (tid & 7) * 8;

  for (int ks = 0; ks < 8; ks++) {
    __syncthreads();
#pragma unroll
    for (int it = 0; it < 4; it++) {
      int row = sr + it * 32;
      const float* src = X + (size_t)(m0 + row) * 512 + ks * 64 + sc;
      float4 a = *(const float4*)(src);
      float4 c = *(const float4*)(src + 4);
      unsigned short tmp[8] = {f2b(a.x), f2b(a.y), f2b(a.z), f2b(a.w),
                               f2b(c.x), f2b(c.y), f2b(c.z), f2b(c.w)};
      *(int4*)(lA + row * 72 + sc) = *(const int4*)tmp;
    }
    __syncthreads();
#pragma unroll
    for (int kk = 0; kk < 2; kk++) {
      short8 af[4], bf[4];
#pragma unroll
      for (int i = 0; i < 4; i++)
        af[i] = *(const short8*)(lA + (wr * 64 + i * 16 + lane16) * 72 + kk * 32 + quad * 8);
#pragma unroll
      for (int j = 0; j < 4; j++) {
        int F = (bn * 8 + wc * 4 + j) * 16 + ks * 2 + kk;
        bf[j] = *(const short8*)(Wp + (size_t)(F * 64 + l) * 8);
      }
#pragma unroll
      for (int i = 0; i < 4; i++)
#pragma unroll
        for (int j = 0; j < 4; j++)
          acc[i][j] = __builtin_amdgcn_mfma_f32_16x16x32_bf16(af[i], bf[j], acc[i][j], 0, 0, 0);
    }
  }
#pragma unroll
  for (int j = 0; j < 4; j++) {
    int n = bn * 128 + wc * 64 + j * 16 + lane16;
    float bj = bias[n];
#pragma unroll
    for (int i = 0; i < 4; i++)
#pragma unroll
      for (int r = 0; r < 4; r++) {
        int m = m0 + wr * 64 + i * 16 + quad * 4 + r;
        xp[(size_t)m * 4096 + n] = f2b(acc[i][j][r] + bj);
      }
  }
}

// ---- Phase C: persistent recurrent kernel — flag-gate-first consume ----
// r3 topology and protocol (128 blocks x 256 thr; tagged-dword transport,
// relaxed agent publish, stride-20 zbuf) with ONE change: the consume side
// polls the cheap 256 B/wave flag gate BEFORE issuing any data pass. The
// 16 KB/wave data pass (8 MB machine-wide per pass at the LLC) then fires
// exactly once per step in the common case, instead of a nearly-always-
// stale first pass + retry. Flags are a HINT (producer's flag store is not
// ordered after its h stores); per-dword tag validation remains the sole
// correctness authority — reordering costs one cheap incremental retry.
__global__ __launch_bounds__(256, 1) void lstm_rec(
    const unsigned short* __restrict__ xp,
    const unsigned short* __restrict__ Up,
    unsigned* __restrict__ hbuf,         // [4][32][1024] dwords
    unsigned* __restrict__ flags,        // [2][64] dwords
    float* __restrict__ out) {           // [32][512][1024] f32
  const int tid = threadIdx.x;
  const int l = tid & 63;
  const int kq = tid >> 6;           // wave = K-quarter
  const int bid = blockIdx.x;        // 0..127
  const int mh = bid >> 6;           // team (batch half)
  const int cg = bid & 63;           // h-col group
  const int quad = l >> 4, lane16 = l & 15;

  // stride 20: 4-quad write pattern tiles 32 banks exactly 2-way (free)
  __shared__ float zbuf[2][4][4][16][20];      // [p][kq][gate][b][col]

  // preload B fragments (U slice) into registers: 4 gates x 8 k-frags x 16B
  short8 bfr[4][8];
#pragma unroll
  for (int g = 0; g < 4; g++)
#pragma unroll
    for (int kk = 0; kk < 8; kk++) {
      int F = ((cg * 4 + kq) * 4 + g) * 8 + kk;
      bfr[g][kk] = *(const short8*)(Up + (size_t)(F * 64 + l) * 8);
    }

  float c_st = 0.0f;
  const int bl = tid >> 4;           // 0..15
  const int jj = tid & 15;
  const int bglob = mh * 16 + bl;

  // consumer base: row = batch (mh*16+lane16), k-quarter kq (dword units)
  const unsigned rowoff = (unsigned)(mh * 16 + lane16) * 1024 + (unsigned)kq * 256;
  // producer store slot (dword units, within slab)
  const unsigned stoff = (unsigned)bglob * 1024 + (unsigned)cg * 16 + jj;
  // flag poll address: lane l watches producer cg=l of team mh
  const unsigned* flgp = flags + mh * 64 + l;
  // flag publish address (block-uniform)
  unsigned* flgst = flags + mh * 64 + cg;

  // xp(0) preload (normal cached; produced by earlier dispatch)
  const unsigned short* xpbase =
      xp + (size_t)bglob * T_SZ * 4096 + (size_t)cg * 16 + jj;
  unsigned short xr0 = xpbase[0];
  unsigned short xr1 = xpbase[1024];
  unsigned short xr2 = xpbase[2048];
  unsigned short xr3 = xpbase[3072];

#pragma unroll 1
  for (int t = 0; t < T_SZ; t++) {
    // ---- consume h(t): flag gate FIRST, then (usually one) data pass ----
    const unsigned tag = (unsigned)t;
    const unsigned* hb32 = hbuf + (size_t)(t & 3) * 32768 + rowoff;
    short8 af[8];
    // cheap flag gate: one coalesced dword load per poll (256 B/wave)
    while (true) {
      unsigned fl;
      asm volatile("global_load_dword %0, %1, off sc0 sc1"
                   : "=v"(fl) : "v"(flgp));
      asm volatile("s_waitcnt vmcnt(0)" ::: "memory");
      __builtin_amdgcn_sched_barrier(0);
      if (__ballot(fl < tag) == 0ull) break;
      __builtin_amdgcn_s_sleep(1);
    }
    unsigned pend = 0xFFu;                       // wave-uniform frag bitmask
    while (pend) {
      u32x4 ra[8], rb[8];
#pragma unroll
      for (int f = 0; f < 8; f++) {
        if (pend & (1u << f)) {
          const unsigned* p = hb32 + f * 32 + quad * 8;
          asm volatile("global_load_dwordx4 %0, %1, off sc0 sc1"
                       : "=v"(ra[f]) : "v"(p));
          asm volatile("global_load_dwordx4 %0, %1, off offset:16 sc0 sc1"
                       : "=v"(rb[f]) : "v"(p));
        }
      }
      asm volatile("s_waitcnt vmcnt(0)" ::: "memory");
      __builtin_amdgcn_sched_barrier(0);
      unsigned np = pend;
#pragma unroll
      for (int f = 0; f < 8; f++) {
        if (pend & (1u << f)) {
          u32x4 a = ra[f], b = rb[f];
          unsigned bad = ((a[0] ^ tag) | (a[1] ^ tag) | (a[2] ^ tag) | (a[3] ^ tag) |
                          (b[0] ^ tag) | (b[1] ^ tag) | (b[2] ^ tag) | (b[3] ^ tag)) & 0xFFFFu;
          if (__ballot(bad != 0u) == 0ull) {
            np &= ~(1u << f);
            u32x4 v = {(a[0] >> 16) | (a[1] & 0xFFFF0000u),
                       (a[2] >> 16) | (a[3] & 0xFFFF0000u),
                       (b[0] >> 16) | (b[1] & 0xFFFF0000u),
                       (b[2] >> 16) | (b[3] & 0xFFFF0000u)};
            af[f] = __builtin_bit_cast(short8, v);
          }
        }
      }
      pend = np;
      if (pend) __builtin_amdgcn_s_sleep(1);
    }

    // ---- z partial GEMM: wave kq covers k in [kq*256, kq*256+256) ----
    f32x4 acc[4];
#pragma unroll
    for (int g = 0; g < 4; g++) acc[g] = (f32x4){0.f, 0.f, 0.f, 0.f};
#pragma unroll
    for (int kk = 0; kk < 8; kk++) {
#pragma unroll
      for (int g = 0; g < 4; g++)
        acc[g] = __builtin_amdgcn_mfma_f32_16x16x32_bf16(af[kk], bfr[g][kk], acc[g], 0, 0, 0);
    }
    const int p = t & 1;
#pragma unroll
    for (int g = 0; g < 4; g++)
#pragma unroll
      for (int r = 0; r < 4; r++)
        zbuf[p][kq][g][quad * 4 + r][lane16] = acc[g][r];
    __syncthreads();                 // the ONLY barrier per step

    // ---- elementwise: thread -> (batch bl, h-col jj) ----
    float z0 = zbuf[p][0][0][bl][jj] + zbuf[p][1][0][bl][jj] + zbuf[p][2][0][bl][jj] + zbuf[p][3][0][bl][jj] + b2f(xr0);
    float z1 = zbuf[p][0][1][bl][jj] + zbuf[p][1][1][bl][jj] + zbuf[p][2][1][bl][jj] + zbuf[p][3][1][bl][jj] + b2f(xr1);
    float z2 = zbuf[p][0][2][bl][jj] + zbuf[p][1][2][bl][jj] + zbuf[p][2][2][bl][jj] + zbuf[p][3][2][bl][jj] + b2f(xr2);
    float z3 = zbuf[p][0][3][bl][jj] + zbuf[p][1][3][bl][jj] + zbuf[p][2][3][bl][jj] + zbuf[p][3][3][bl][jj] + b2f(xr3);
    float ig = sigm(z0);
    float fg = sigm(z1);
    float gg = tanh_f(z2);
    float og = sigm(z3);
    c_st = fg * c_st + ig * gg;
    float h = og * tanh_f(c_st);

    // ---- publish h(t+1): tagged dword, write-through, no ordering needed ----
    unsigned tagged = ((unsigned)f2b(h) << 16) | (unsigned)(t + 1);
    __hip_atomic_store(hbuf + (size_t)((t + 1) & 3) * 32768 + stoff, tagged,
                       __ATOMIC_RELAXED, __HIP_MEMORY_SCOPE_AGENT);
    // flag hint: this block has published step t+1 (unordered; tags validate)
    if (tid == 0)
      __hip_atomic_store(flgst, (unsigned)(t + 1),
                         __ATOMIC_RELAXED, __HIP_MEMORY_SCOPE_AGENT);

    // tail (overlaps other blocks' progress): out store + xp(t+1) prefetch
    out[((size_t)bglob * T_SZ + t) * 1024 + cg * 16 + jj] = h;
    {
      int tn = (t + 1 < T_SZ) ? t + 1 : t;
      const unsigned short* xpn = xpbase + (size_t)tn * 4096;
      xr0 = xpn[0];
      xr1 = xpn[1024];
      xr2 = xpn[2048];
      xr3 = xpn[3072];
    }
  }
}

extern "C" void kernel_launch(void* const* d_in, const int* in_sizes, int n_in,
                              void* d_out, int out_size, void* d_ws, size_t ws_size,
                              hipStream_t stream) {
  const float* X    = (const float*)d_in[0];  // [32][512][512]  f32
  const float* W    = (const float*)d_in[1];  // [512][4096]     f32
  const float* U    = (const float*)d_in[2];  // [1024][4096]    f32
  const float* bias = (const float*)d_in[3];  // [4096]          f32
  float* out = (float*)d_out;                 // [32][512][1024] f32

  char* ws = (char*)d_ws;
  unsigned short* xp    = (unsigned short*)(ws + XP_OFF);
  unsigned short* Up    = (unsigned short*)(ws + UPERM_OFF);
  unsigned short* Wp    = (unsigned short*)(ws + WPERM_OFF);
  unsigned*       hbuf  = (unsigned*)(ws + HBUF_OFF);
  unsigned*       flags = (unsigned*)(ws + FLAGS_OFF);

  hipLaunchKernelGGL(permute_U, dim3(2048), dim3(256), 0, stream, U, Up);
  hipLaunchKernelGGL(permute_W, dim3(1024), dim3(256), 0, stream, W, Wp);
  hipLaunchKernelGGL(init_hbuf, dim3(513), dim3(256), 0, stream, hbuf, flags);
  hipLaunchKernelGGL(xproj_gemm, dim3(32, 128), dim3(256), 0, stream, X, Wp, bias, xp);
  hipLaunchKernelGGL(lstm_rec, dim3(128), dim3(256), 0, stream, xp, Up, hbuf, flags, out);
}

// Round 15
// 2821.926 us; speedup vs baseline: 4.7801x; 1.0609x over previous
//
#include <hip/hip_runtime.h>
#include <stdint.h>

typedef __attribute__((ext_vector_type(8))) short short8;
typedef __attribute__((ext_vector_type(4))) float f32x4;
typedef __attribute__((ext_vector_type(4))) unsigned u32x4;

#define T_SZ 512

// ws layout (bytes)
#define XP_OFF    0ull                 // xp (bf16): 16384*4096*2 = 134217728
#define UPERM_OFF 134217728ull         // Uperm (bf16): 8 MB
#define WPERM_OFF 142606336ull         // Wperm (bf16): 4 MB
#define HBUF_OFF  146800640ull         // hbuf: 4 slabs x 32 x 1024 dwords = 512 KB
#define FLAGS_OFF 147324928ull         // flags: 2 teams x 64 producers dwords
#define CNT_OFF   147325440ull         // 4 dwords: xp t-block completion counters

static __device__ __forceinline__ float b2f(unsigned short u) {
  unsigned v = ((unsigned)u) << 16;
  return __builtin_bit_cast(float, v);
}
static __device__ __forceinline__ unsigned short f2b(float f) {
  unsigned u = __builtin_bit_cast(unsigned, f);
  u += 0x7fffu + ((u >> 16) & 1u);   // RNE
  return (unsigned short)(u >> 16);
}
static __device__ __forceinline__ float sigm(float x) {
  return 1.0f / (1.0f + __expf(-x));
}
static __device__ __forceinline__ float tanh_f(float x) {
  return 1.0f - 2.0f / (__expf(2.0f * x) + 1.0f);
}
// LLC-bypass 2-byte load; result valid only after a later s_waitcnt vmcnt(0)
// (the h-spin's wait covers it before any use).
static __device__ __forceinline__ unsigned ldus(const unsigned short* p) {
  unsigned r;
  asm volatile("global_load_ushort %0, %1, off sc0 sc1" : "=v"(r) : "v"(p));
  return r;
}

// ---- one-time permutation of U (f32 -> bf16) into MFMA B-fragment layout ----
__global__ void permute_U(const float* __restrict__ U, unsigned short* __restrict__ Up) {
  int t = blockIdx.x * 256 + threadIdx.x;        // 524288 threads
  int l = t & 63;
  int F = t >> 6;                                 // 8192 frags
  int kk = F & 7, g = (F >> 3) & 3, kq = (F >> 5) & 3, cg = F >> 7;
  int k0 = kq * 256 + kk * 32 + (l >> 4) * 8;
  int n  = g * 1024 + cg * 16 + (l & 15);
  unsigned short v[8];
#pragma unroll
  for (int j = 0; j < 8; j++) v[j] = f2b(U[(size_t)(k0 + j) * 4096 + n]);
  unsigned short* dst = Up + (size_t)t * 8;
#pragma unroll
  for (int j = 0; j < 8; j++) dst[j] = v[j];
}

__global__ void permute_W(const float* __restrict__ W, unsigned short* __restrict__ Wp) {
  int t = blockIdx.x * 256 + threadIdx.x;        // 262144 threads
  int l = t & 63;
  int F = t >> 6;                                 // 4096 frags
  int kk = F & 15, nt = F >> 4;
  int k0 = kk * 32 + (l >> 4) * 8;
  int n  = nt * 16 + (l & 15);
  unsigned short v[8];
#pragma unroll
  for (int j = 0; j < 8; j++) v[j] = f2b(W[(size_t)(k0 + j) * 4096 + n]);
  unsigned short* dst = Wp + (size_t)t * 8;
#pragma unroll
  for (int j = 0; j < 8; j++) dst[j] = v[j];
}

// hbuf: 4 slabs x 32768 dwords. slab 0 = (h=0, tag=0); slabs 1..3 = tag 0xFFFF.
// flags: 128 producer step flags, cnt: 4 xp t-block counters. All zeroed.
__global__ void init_hbuf(unsigned* __restrict__ hbuf, unsigned* __restrict__ flags,
                          unsigned* __restrict__ cnt) {
  int t = blockIdx.x * 256 + threadIdx.x;        // 513*256 threads
  if (t < 131072) hbuf[t] = (t < 32768) ? 0u : 0xFFFFu;
  else if (t < 131072 + 128) flags[t - 131072] = 0u;
  else if (t < 131072 + 132) cnt[t - 131200] = 0u;
}

// ---- Fused persistent kernel ----
// blocks 0..127   : lstm role — EXACT r3 transport (best measured: 2208 us).
// blocks 128..4223: xproj tiles, t-MAJOR order (tb = (bx-128)>>10) so early
//   timesteps are produced first. Stores xp with sc0sc1 (write-through to
//   the LLC), vmcnt(0)+barrier, then release-atomicAdd on cnt[tb]. 1024
//   blocks per tb. lstm gates each 128-step t-block on cnt[tb]==1024
//   (acquire) before prefetching its xp, and reads xp with sc0sc1 bypass
//   loads — no stale-L2 hazard, no ordering assumptions beyond the
//   release/acquire pair. Deadlock-free: lstm blocks are dispatched first
//   and all fit (128 <= 256 CUs); xproj blocks never wait on anything.
__global__ __launch_bounds__(256, 1) void fused(
    const float* __restrict__ X,
    const unsigned short* __restrict__ Wp,
    const float* __restrict__ bias,
    unsigned short* __restrict__ xp,
    const unsigned short* __restrict__ Up,
    unsigned* __restrict__ hbuf,         // [4][32][1024] dwords
    unsigned* __restrict__ flags,        // [2][64] dwords
    unsigned* __restrict__ cnt,          // [4] dwords
    float* __restrict__ out) {           // [32][512][1024] f32
  const int tid = threadIdx.x;
  const int l = tid & 63;
  const int quad = l >> 4, lane16 = l & 15;

  __shared__ char smem_raw[40960];       // union: zbuf (40960) / lA (18432)

  if (blockIdx.x >= 128) {
    // ================= xproj role =================
    const int bx = blockIdx.x - 128;     // 0..4095
    const int bn = bx & 31;
    const int b  = (bx >> 5) & 31;
    const int tb = bx >> 10;             // 0..3 (t-major: tb=0 first)
    const int m0 = b * 512 + tb * 128;
    const int w = tid >> 6;
    const int wr = w >> 1, wc = w & 1;
    unsigned short* lA = (unsigned short*)smem_raw;   // [128*72]

    f32x4 acc[4][4];
#pragma unroll
    for (int i = 0; i < 4; i++)
#pragma unroll
      for (int j = 0; j < 4; j++) acc[i][j] = (f32x4){0.f, 0.f, 0.f, 0.f};

    const int sr = tid >> 3;
    const int sc = (tid & 7) * 8;

    for (int ks = 0; ks < 8; ks++) {
      __syncthreads();
#pragma unroll
      for (int it = 0; it < 4; it++) {
        int row = sr + it * 32;
        const float* src = X + (size_t)(m0 + row) * 512 + ks * 64 + sc;
        float4 a = *(const float4*)(src);
        float4 c = *(const float4*)(src + 4);
        unsigned short tmp[8] = {f2b(a.x), f2b(a.y), f2b(a.z), f2b(a.w),
                                 f2b(c.x), f2b(c.y), f2b(c.z), f2b(c.w)};
        *(int4*)(lA + row * 72 + sc) = *(const int4*)tmp;
      }
      __syncthreads();
#pragma unroll
      for (int kk = 0; kk < 2; kk++) {
        short8 af[4], bf[4];
#pragma unroll
        for (int i = 0; i < 4; i++)
          af[i] = *(const short8*)(lA + (wr * 64 + i * 16 + lane16) * 72 + kk * 32 + quad * 8);
#pragma unroll
        for (int j = 0; j < 4; j++) {
          int F = (bn * 8 + wc * 4 + j) * 16 + ks * 2 + kk;
          bf[j] = *(const short8*)(Wp + (size_t)(F * 64 + l) * 8);
        }
#pragma unroll
        for (int i = 0; i < 4; i++)
#pragma unroll
          for (int j = 0; j < 4; j++)
            acc[i][j] = __builtin_amdgcn_mfma_f32_16x16x32_bf16(af[i], bf[j], acc[i][j], 0, 0, 0);
      }
    }
#pragma unroll
    for (int j = 0; j < 4; j++) {
      int n = bn * 128 + wc * 64 + j * 16 + lane16;
      float bj = bias[n];
#pragma unroll
      for (int i = 0; i < 4; i++)
#pragma unroll
        for (int r = 0; r < 4; r++) {
          int m = m0 + wr * 64 + i * 16 + quad * 4 + r;
          unsigned hv = (unsigned)f2b(acc[i][j][r] + bj);
          const unsigned short* ptr = xp + (size_t)m * 4096 + n;
          asm volatile("global_store_short %0, %1, off sc0 sc1"
                       :: "v"(ptr), "v"(hv) : "memory");
        }
    }
    asm volatile("s_waitcnt vmcnt(0)" ::: "memory");
    __syncthreads();
    if (tid == 0)
      __hip_atomic_fetch_add(&cnt[tb], 1u, __ATOMIC_RELEASE, __HIP_MEMORY_SCOPE_AGENT);
    return;
  }

  // ================= lstm role (exact r3 transport) =================
  const int kq = tid >> 6;           // wave = K-quarter
  const int bid = blockIdx.x;        // 0..127
  const int mh = bid >> 6;           // team (batch half)
  const int cg = bid & 63;           // h-col group

  // stride 20: 4-quad write pattern tiles 32 banks exactly 2-way (free)
  float (*zbuf)[4][4][16][20] = (float (*)[4][4][16][20])smem_raw;  // [2][...]

  // preload B fragments (U slice) into registers: 4 gates x 8 k-frags x 16B
  short8 bfr[4][8];
#pragma unroll
  for (int g = 0; g < 4; g++)
#pragma unroll
    for (int kk = 0; kk < 8; kk++) {
      int F = ((cg * 4 + kq) * 4 + g) * 8 + kk;
      bfr[g][kk] = *(const short8*)(Up + (size_t)(F * 64 + l) * 8);
    }

  float c_st = 0.0f;
  const int bl = tid >> 4;           // 0..15
  const int jj = tid & 15;
  const int bglob = mh * 16 + bl;

  // consumer base: row = batch (mh*16+lane16), k-quarter kq (dword units)
  const unsigned rowoff = (unsigned)(mh * 16 + lane16) * 1024 + (unsigned)kq * 256;
  // producer store slot (dword units, within slab)
  const unsigned stoff = (unsigned)bglob * 1024 + (unsigned)cg * 16 + jj;
  // flag poll address: lane l watches producer cg=l of team mh
  const unsigned* flgp = flags + mh * 64 + l;
  // flag publish address (block-uniform)
  unsigned* flgst = flags + mh * 64 + cg;

  const unsigned short* xpbase =
      xp + (size_t)bglob * T_SZ * 4096 + (size_t)cg * 16 + jj;

  // gate xp t-block 0, then prefetch xr(0) (bypass loads; covered by the
  // t=0 h-spin's vmcnt(0))
  int ready_tb = -1;
  {
    while (true) {
      unsigned c = __hip_atomic_load(&cnt[0], __ATOMIC_ACQUIRE, __HIP_MEMORY_SCOPE_AGENT);
      if (c >= 1024u) break;
      __builtin_amdgcn_s_sleep(4);
    }
    ready_tb = 0;
  }
  unsigned xr0 = ldus(xpbase + 0);
  unsigned xr1 = ldus(xpbase + 1024);
  unsigned xr2 = ldus(xpbase + 2048);
  unsigned xr3 = ldus(xpbase + 3072);

#pragma unroll 1
  for (int t = 0; t < T_SZ; t++) {
    // ---- consume h(t): speculative data pass, then cheap flag-gated retry ----
    const unsigned tag = (unsigned)t;
    const unsigned* hb32 = hbuf + (size_t)(t & 3) * 32768 + rowoff;
    short8 af[8];
    unsigned pend = 0xFFu;                       // wave-uniform frag bitmask
    bool first = true;
    while (pend) {
      if (!first) {
        // cheap flag gate: one coalesced dword load per pass (256 B/wave)
        while (true) {
          unsigned fl;
          asm volatile("global_load_dword %0, %1, off sc0 sc1"
                       : "=v"(fl) : "v"(flgp));
          asm volatile("s_waitcnt vmcnt(0)" ::: "memory");
          __builtin_amdgcn_sched_barrier(0);
          if (__ballot(fl < tag) == 0ull) break;
          __builtin_amdgcn_s_sleep(1);
        }
      }
      first = false;
      u32x4 ra[8], rb[8];
#pragma unroll
      for (int f = 0; f < 8; f++) {
        if (pend & (1u << f)) {
          const unsigned* p = hb32 + f * 32 + quad * 8;
          asm volatile("global_load_dwordx4 %0, %1, off sc0 sc1"
                       : "=v"(ra[f]) : "v"(p));
          asm volatile("global_load_dwordx4 %0, %1, off offset:16 sc0 sc1"
                       : "=v"(rb[f]) : "v"(p));
        }
      }
      asm volatile("s_waitcnt vmcnt(0)" ::: "memory");
      __builtin_amdgcn_sched_barrier(0);
      unsigned np = pend;
#pragma unroll
      for (int f = 0; f < 8; f++) {
        if (pend & (1u << f)) {
          u32x4 a = ra[f], b = rb[f];
          unsigned bad = ((a[0] ^ tag) | (a[1] ^ tag) | (a[2] ^ tag) | (a[3] ^ tag) |
                          (b[0] ^ tag) | (b[1] ^ tag) | (b[2] ^ tag) | (b[3] ^ tag)) & 0xFFFFu;
          if (__ballot(bad != 0u) == 0ull) {
            np &= ~(1u << f);
            u32x4 v = {(a[0] >> 16) | (a[1] & 0xFFFF0000u),
                       (a[2] >> 16) | (a[3] & 0xFFFF0000u),
                       (b[0] >> 16) | (b[1] & 0xFFFF0000u),
                       (b[2] >> 16) | (b[3] & 0xFFFF0000u)};
            af[f] = __builtin_bit_cast(short8, v);
          }
        }
      }
      pend = np;
    }

    // ---- z partial GEMM: wave kq covers k in [kq*256, kq*256+256) ----
    f32x4 acc[4];
#pragma unroll
    for (int g = 0; g < 4; g++) acc[g] = (f32x4){0.f, 0.f, 0.f, 0.f};
#pragma unroll
    for (int kk = 0; kk < 8; kk++) {
#pragma unroll
      for (int g = 0; g < 4; g++)
        acc[g] = __builtin_amdgcn_mfma_f32_16x16x32_bf16(af[kk], bfr[g][kk], acc[g], 0, 0, 0);
    }
    const int p = t & 1;
#pragma unroll
    for (int g = 0; g < 4; g++)
#pragma unroll
      for (int r = 0; r < 4; r++)
        zbuf[p][kq][g][quad * 4 + r][lane16] = acc[g][r];
    __syncthreads();                 // the ONLY barrier per step

    // ---- elementwise: thread -> (batch bl, h-col jj) ----
    float z0 = zbuf[p][0][0][bl][jj] + zbuf[p][1][0][bl][jj] + zbuf[p][2][0][bl][jj] + zbuf[p][3][0][bl][jj] + b2f((unsigned short)xr0);
    float z1 = zbuf[p][0][1][bl][jj] + zbuf[p][1][1][bl][jj] + zbuf[p][2][1][bl][jj] + zbuf[p][3][1][bl][jj] + b2f((unsigned short)xr1);
    float z2 = zbuf[p][0][2][bl][jj] + zbuf[p][1][2][bl][jj] + zbuf[p][2][2][bl][jj] + zbuf[p][3][2][bl][jj] + b2f((unsigned short)xr2);
    float z3 = zbuf[p][0][3][bl][jj] + zbuf[p][1][3][bl][jj] + zbuf[p][2][3][bl][jj] + zbuf[p][3][3][bl][jj] + b2f((unsigned short)xr3);
    float ig = sigm(z0);
    float fg = sigm(z1);
    float gg = tanh_f(z2);
    float og = sigm(z3);
    c_st = fg * c_st + ig * gg;
    float h = og * tanh_f(c_st);

    // ---- publish h(t+1): tagged dword, write-through, no ordering needed ----
    unsigned tagged = ((unsigned)f2b(h) << 16) | (unsigned)(t + 1);
    __hip_atomic_store(hbuf + (size_t)((t + 1) & 3) * 32768 + stoff, tagged,
                       __ATOMIC_RELAXED, __HIP_MEMORY_SCOPE_AGENT);
    // flag hint: this block has published step t+1 (unordered; tags validate)
    if (tid == 0)
      __hip_atomic_store(flgst, (unsigned)(t + 1),
                         __ATOMIC_RELAXED, __HIP_MEMORY_SCOPE_AGENT);

    // tail: out store + gated xp(t+1) prefetch (bypass loads; covered by
    // the next step's h-spin vmcnt(0))
    out[((size_t)bglob * T_SZ + t) * 1024 + cg * 16 + jj] = h;
    {
      int tn = (t + 1 < T_SZ) ? t + 1 : t;
      int tbn = tn >> 7;
      if (tbn > ready_tb) {
        while (true) {
          unsigned c = __hip_atomic_load(&cnt[tbn], __ATOMIC_ACQUIRE, __HIP_MEMORY_SCOPE_AGENT);
          if (c >= 1024u) break;
          __builtin_amdgcn_s_sleep(2);
        }
        ready_tb = tbn;
      }
      const unsigned short* xpn = xpbase + (size_t)tn * 4096;
      xr0 = ldus(xpn + 0);
      xr1 = ldus(xpn + 1024);
      xr2 = ldus(xpn + 2048);
      xr3 = ldus(xpn + 3072);
    }
  }
}

extern "C" void kernel_launch(void* const* d_in, const int* in_sizes, int n_in,
                              void* d_out, int out_size, void* d_ws, size_t ws_size,
                              hipStream_t stream) {
  const float* X    = (const float*)d_in[0];  // [32][512][512]  f32
  const float* W    = (const float*)d_in[1];  // [512][4096]     f32
  const float* U    = (const float*)d_in[2];  // [1024][4096]    f32
  const float* bias = (const float*)d_in[3];  // [4096]          f32
  float* out = (float*)d_out;                 // [32][512][1024] f32

  char* ws = (char*)d_ws;
  unsigned short* xp    = (unsigned short*)(ws + XP_OFF);
  unsigned short* Up    = (unsigned short*)(ws + UPERM_OFF);
  unsigned short* Wp    = (unsigned short*)(ws + WPERM_OFF);
  unsigned*       hbuf  = (unsigned*)(ws + HBUF_OFF);
  unsigned*       flags = (unsigned*)(ws + FLAGS_OFF);
  unsigned*       cnt   = (unsigned*)(ws + CNT_OFF);

  hipLaunchKernelGGL(permute_U, dim3(2048), dim3(256), 0, stream, U, Up);
  hipLaunchKernelGGL(permute_W, dim3(1024), dim3(256), 0, stream, W, Wp);
  hipLaunchKernelGGL(init_hbuf, dim3(513), dim3(256), 0, stream, hbuf, flags, cnt);
  hipLaunchKernelGGL(fused, dim3(128 + 4096), dim3(256), 0, stream,
                     X, Wp, bias, xp, Up, hbuf, flags, cnt, out);
}